// Round 22
// baseline (350.142 us; speedup 1.0000x reference)
//
#include <hip/hip_runtime.h>

#define KN 32768
#define KE 65536
#define KB 512
#define KEPB 64
#define KNREG 33
#define KEORD (KE + KNREG * KEPB)   /* 67648 padded sorted-edge slots */
#define KNBLK (KEORD / KEPB)        /* 1057 edge blocks */

/* ---------------- workspace element offsets ---------------- */
/* zero-init zone */
#define O_BUF0 ((size_t)0)
#define O_BUF1 (O_BUF0 + (size_t)KN * 64)
#define O_DEG  (O_BUF1 + (size_t)KN * 64)
#define O_GCNT (O_DEG + KN)
#define O_GST  (O_GCNT + KB)
#define O_HIST (O_GST + KB + 8)          /* [2][64] */
#define O_CUR  (O_HIST + 128)            /* [2][64] */
#define O_FLAG (O_CUR + 128)
#define O_ZEND (O_FLAG + 64)
/* -1-init zone */
#define O_EORD ((O_ZEND + 63) & ~(size_t)63)    /* [2][KEORD] */
#define O_RBLK (O_EORD + 2 * (size_t)KEORD)     /* [2][1088] */
#define O_FEND (O_RBLK + 2 * 1088)
/* no-init zone (fully written before read) */
#define O_WB   ((O_FEND + 63) & ~(size_t)63)    /* [33][4096] */
#define O_WS   (O_WB + (size_t)KNREG * 4096)
#define O_CROSS (O_WS + (size_t)KNREG * 4096)   /* [64]: 32 per layer */
#define O_RCNT (O_CROSS + 64)                    /* [2] */
#define O_AOFF (O_RCNT + 64)                     /* [2][64] */
#define O_END  (O_AOFF + 128)

/* transposed LSTM weights in dead eorder region (refilled every call). */
#define T_WIH0 (O_EORD)
#define T_WHH0 (T_WIH0 + 32768)
#define T_WIH1 (T_WHH0 + 16384)
#define T_WHH1 (T_WIH1 + 16384)
#define T_WIH2 (T_WHH1 + 16384)
#define T_WHH2 (T_WIH2 + 16384)     /* end = O_EORD + 114688 <= O_RBLK */

__device__ float sigf(float x) { return 1.0f / (1.0f + expf(-x)); }

/* diagnostic fill (f32 output) */
extern "C" __global__ void GNNModule_9259949490279_kernel(float* out, float v) {
    int i = blockIdx.x * 256 + threadIdx.x;
    if (i < KB * 64) out[i] = v;
}

extern "C" __global__ void k_post(const int* flag, float* out) {
    int f = flag[0];
    if (f == 0) return;
    int i = blockIdx.x * 256 + threadIdx.x;
    if (i < KB * 64) out[i] = 300.0f + (float)f;
}

/* merged: zero-zone + (-1)-zone init in one launch */
extern "C" __global__ void k_init(float* wsf, int* wsi) {
    size_t i = (size_t)blockIdx.x * 256 + threadIdx.x;
    size_t stride = (size_t)gridDim.x * 256;
    for (size_t p = i; p < O_ZEND; p += stride) wsf[p] = 0.0f;
    for (size_t p = O_EORD + i; p < O_FEND; p += stride) wsi[p] = -1;
}

/* both layers' ReLU breakpoints: block l handles layer l */
extern "C" __global__ void k_prepall(
    const float* ew1a, const float* eb1a, const float* ew1b, const float* eb1b,
    float* cross, int* rcnt) {
    __shared__ float la[32], lb_[32];
    int l = blockIdx.x;
    int t = threadIdx.x;
    const float* w = (l == 0) ? ew1a : ew1b;
    const float* b = (l == 0) ? eb1a : eb1b;
    if (t < 32) { la[t] = w[t]; lb_[t] = b[t]; }
    __syncthreads();
    if (t == 0) {
        float cl[32];
        int n = 0;
        for (int k = 0; k < 32; ++k) {
            float a = la[k], bb = lb_[k];
            if (a != 0.0f) {
                float tt = -bb / a;
                if (tt > 0.0f && tt < 1.0f) cl[n++] = tt;
            }
        }
        for (int i = 1; i < n; ++i) {
            float v = cl[i];
            int j = i - 1;
            while (j >= 0 && cl[j] > v) { cl[j + 1] = cl[j]; --j; }
            cl[j + 1] = v;
        }
        for (int i = 0; i < n; ++i) cross[32 * l + i] = cl[i];
        rcnt[l] = n;
    }
}

/* fused front sweep: deg + gcount + region hists (both layers) */
extern "C" __global__ void k_front(
    const int* dst, const int* gid, const float* efeat,
    const float* cross, const int* rcnt,
    float* deg, int* gcnt, int* hist0, int* hist1, int* flag) {
    __shared__ float c0[32], c1[32];
    __shared__ int n0s, n1s;
    __shared__ int lh0[64], lh1[64];
    __shared__ int lg[192];
    __shared__ int gminS;
    int t = threadIdx.x;
    int b = blockIdx.x;
    if (t < 32) { c0[t] = cross[t]; c1[t] = cross[32 + t]; }
    if (t == 0) { n0s = rcnt[0]; n1s = rcnt[1]; gminS = gid[b * 128]; }
    if (t < 64) { lh0[t] = 0; lh1[t] = 0; }
    if (t < 192) lg[t] = 0;
    __syncthreads();
    int e = b * 256 + t;
    int d = dst[e];
    if ((unsigned)d >= (unsigned)KN) { atomicOr(flag, 1); d = 0; }
    atomicAdd(&deg[d], 1.0f);
    float f = efeat[e];
    int r0 = 0, r1 = 0;
    int n0 = n0s, n1 = n1s;
    for (int j = 0; j < n0; ++j) r0 += (f > c0[j]) ? 1 : 0;
    for (int j = 0; j < n1; ++j) r1 += (f > c1[j]) ? 1 : 0;
    atomicAdd(&lh0[r0], 1);
    atomicAdd(&lh1[r1], 1);
    if (t < 128) {
        int n = b * 128 + t;
        int g = gid[n];
        if ((unsigned)g >= (unsigned)KB) { atomicOr(flag, 2); g = 0; }
        int gm = gminS;
        if ((unsigned)gm >= (unsigned)KB) gm = 0;
        int dd = g - gm;
        if (dd >= 0 && dd < 192) atomicAdd(&lg[dd], 1);
        else atomicAdd(&gcnt[g], 1);
    }
    __syncthreads();
    if (t < 64) {
        if (lh0[t] > 0) atomicAdd(&hist0[t], lh0[t]);
        if (lh1[t] > 0) atomicAdd(&hist1[t], lh1[t]);
    }
    if (t < 192 && lg[t] > 0) {
        int gm = gminS;
        if ((unsigned)gm >= (unsigned)KB) gm = 0;
        int gidx = gm + t;
        if (gidx <= KB) atomicAdd(&gcnt[gidx], lg[t]);
    }
}

/* block 0: gscan; blocks 1,2: region scans */
extern "C" __global__ void k_scans(
    const int* gcnt, int* gstart,
    const int* histb, const int* rcnt, int* aoffb, int* rblkb) {
    int t = threadIdx.x;
    if (blockIdx.x == 0) {
        __shared__ int part[64];
        __shared__ int pre[64];
        int v[8];
        int s = 0;
        int base = t * 8;
        for (int j = 0; j < 8; ++j) { v[j] = gcnt[base + j]; s += v[j]; }
        part[t] = s;
        __syncthreads();
        if (t == 0) {
            int run = 0;
            for (int i = 0; i < 64; ++i) { pre[i] = run; run += part[i]; }
        }
        __syncthreads();
        int run = pre[t];
        for (int j = 0; j < 8; ++j) { gstart[base + j] = run; run += v[j]; }
        if (t == 63) gstart[KB] = run;
    } else {
        int l = blockIdx.x - 1;
        const int* hist = histb + l * 64;
        int* aoff = aoffb + l * 64;
        int* rblk = rblkb + l * 1088;
        __shared__ int lh[64];
        lh[t] = hist[t];
        __syncthreads();
        int R = rcnt[l] + 1;
        if (t < R) {
            int base = 0;
            for (int r = 0; r < t; ++r) base += (lh[r] + KEPB - 1) / KEPB;
            aoff[t] = base * KEPB;
            int nb = (lh[t] + KEPB - 1) / KEPB;
            for (int j = 0; j < nb; ++j) rblk[base + j] = t;
        }
    }
}

/* blocks 0-255: dual-layer scatidx; blocks 256+: mats layer 0 */
extern "C" __global__ __launch_bounds__(256) void k_mid(
    const float* efeat, const float* cross, const int* rcnt,
    const int* aoffb, int* cursorb, int* eorder0, int* eorder1,
    const float* ew1, const float* eb1, const float* ew2, const float* eb2,
    float* Wb, float* Ws) {
    int t = threadIdx.x;
    if (blockIdx.x < 256) {
        __shared__ float c0[32], c1[32];
        __shared__ int n0s, n1s;
        __shared__ int lc0[64], lc1[64], lb0[64], lb1[64];
        int b = blockIdx.x;
        if (t < 32) { c0[t] = cross[t]; c1[t] = cross[32 + t]; }
        if (t == 0) { n0s = rcnt[0]; n1s = rcnt[1]; }
        if (t < 64) { lc0[t] = 0; lc1[t] = 0; }
        __syncthreads();
        int e = b * 256 + t;
        float f = efeat[e];
        int r0 = 0, r1 = 0;
        int n0 = n0s, n1 = n1s;
        for (int j = 0; j < n0; ++j) r0 += (f > c0[j]) ? 1 : 0;
        for (int j = 0; j < n1; ++j) r1 += (f > c1[j]) ? 1 : 0;
        int lr0 = atomicAdd(&lc0[r0], 1);
        int lr1 = atomicAdd(&lc1[r1], 1);
        __syncthreads();
        if (t < 64) {
            if (lc0[t] > 0) lb0[t] = atomicAdd(&cursorb[t], lc0[t]);
            if (lc1[t] > 0) lb1[t] = atomicAdd(&cursorb[64 + t], lc1[t]);
        }
        __syncthreads();
        eorder0[aoffb[r0] + lb0[r0] + lr0] = e;
        eorder1[aoffb[64 + r1] + lb1[r1] + lr1] = e;
    } else {
        int r = blockIdx.x - 256;
        int n = rcnt[0];
        if (r > n) return;
        float lo = (r == 0) ? 0.0f : cross[r - 1];
        float hi = (r == n) ? 1.0f : cross[r];
        float mid = 0.5f * (lo + hi);
        __shared__ float mw[32], mb[32];
        if (t < 32) {
            bool act = (mid * ew1[t] + eb1[t]) > 0.0f;
            mw[t] = act ? ew1[t] : 0.0f;
            mb[t] = act ? eb1[t] : 0.0f;
        }
        __syncthreads();
        #pragma unroll
        for (int j = 0; j < 16; ++j) {
            int idx = j * 256 + t;
            float as = 0.0f, ab = eb2[idx];
            #pragma unroll
            for (int k4 = 0; k4 < 8; ++k4) {
                float4 w2 = *(const float4*)&ew2[(size_t)idx * 32 + 4 * k4];
                as += mw[4*k4+0]*w2.x + mw[4*k4+1]*w2.y + mw[4*k4+2]*w2.z + mw[4*k4+3]*w2.w;
                ab += mb[4*k4+0]*w2.x + mb[4*k4+1]*w2.y + mb[4*k4+2]*w2.z + mb[4*k4+3]*w2.w;
            }
            Wb[(size_t)r * 4096 + idx] = ab;
            Ws[(size_t)r * 4096 + idx] = as;
        }
    }
}

/* ---- edge message + scatter (HW-verified, verbatim) ---- */
extern "C" __global__ __launch_bounds__(256) void k_edge(
    const float* x, const float* efeat, const int* src, const int* dst,
    const float* Wb, const float* Ws, const int* rblk, const int* eorder,
    float* sbuf) {
    __shared__ __align__(16) float mbuf[4096];
    __shared__ __align__(16) float msuf[4096];
    __shared__ __align__(16) float xs[4][16][64];
    int b = blockIdx.x;
    int r = rblk[b];
    if (r < 0) return;
    int t = threadIdx.x;
    const float4* gb = (const float4*)(Wb + (size_t)r * 4096);
    const float4* gs = (const float4*)(Ws + (size_t)r * 4096);
    float4* lb = (float4*)mbuf;
    float4* ls = (float4*)msuf;
    #pragma unroll
    for (int j = 0; j < 4; ++j) {
        lb[t + 256 * j] = gb[t + 256 * j];
        ls[t + 256 * j] = gs[t + 256 * j];
    }
    __syncthreads();
    int w = t >> 6, lane = t & 63;
    int base = b * KEPB + w * 16;
    int eid = (lane < 16) ? eorder[base + lane] : -1;
    float efl = 0.0f;
    int srl = 0, dsl = 0;
    if (eid >= 0) { efl = efeat[eid]; srl = src[eid]; dsl = dst[eid]; }
    unsigned long long vm = __ballot(eid >= 0);
    if ((vm & 0xFFFFull) == 0ull) return;
    float ef[16];
    int dv[16];
    #pragma unroll
    for (int s = 0; s < 16; ++s) {
        ef[s] = __shfl(efl, s);
        int sv = __shfl(srl, s);
        dv[s] = __shfl(dsl, s);
        xs[w][s][lane] = x[(size_t)sv * 64 + lane];
    }
    float acc[16];
    #pragma unroll
    for (int s = 0; s < 16; ++s) acc[s] = 0.0f;
    #pragma unroll 1
    for (int i4 = 0; i4 < 16; ++i4) {
        float wb0 = mbuf[(i4 * 4 + 0) * 64 + lane], ws0 = msuf[(i4 * 4 + 0) * 64 + lane];
        float wb1 = mbuf[(i4 * 4 + 1) * 64 + lane], ws1 = msuf[(i4 * 4 + 1) * 64 + lane];
        float wb2 = mbuf[(i4 * 4 + 2) * 64 + lane], ws2 = msuf[(i4 * 4 + 2) * 64 + lane];
        float wb3 = mbuf[(i4 * 4 + 3) * 64 + lane], ws3 = msuf[(i4 * 4 + 3) * 64 + lane];
        #pragma unroll
        for (int j = 0; j < 16; ++j) {
            float4 xv = *(const float4*)&xs[w][j][i4 * 4];
            acc[j] = fmaf(xv.x, fmaf(ef[j], ws0, wb0), acc[j]);
            acc[j] = fmaf(xv.y, fmaf(ef[j], ws1, wb1), acc[j]);
            acc[j] = fmaf(xv.z, fmaf(ef[j], ws2, wb2), acc[j]);
            acc[j] = fmaf(xv.w, fmaf(ef[j], ws3, wb3), acc[j]);
        }
    }
    #pragma unroll
    for (int j = 0; j < 16; ++j) {
        if ((vm >> j) & 1ull) atomicAdd(&sbuf[(size_t)dv[j] * 64 + lane], acc[j]);
    }
}

/* fused: final0 (blocks 0..8191) + mats layer1 (blocks 8192..8192+32) */
extern "C" __global__ __launch_bounds__(256) void k_fin0mats(
    float* s, const float* deg, const float* cb, int* flag,
    const float* ew1, const float* eb1, const float* ew2, const float* eb2,
    const float* cross, const int* rcnt, float* Wb, float* Ws) {
    int t = threadIdx.x;
    if (blockIdx.x < 8192) {
        int idx = blockIdx.x * 256 + t;
        int n = idx >> 6;
        int o = idx & 63;
        float d = deg[n];
        if (d < 1.0f) d = 1.0f;
        float v = s[idx] / d + cb[o];
        if (v < 0.0f) v = 0.0f;
        if (!(v == v)) { v = 0.0f; atomicOr(flag, 32); }
        s[idx] = v;
    } else {
        int r = blockIdx.x - 8192;
        int n = *rcnt;
        if (r > n) return;
        float lo = (r == 0) ? 0.0f : cross[r - 1];
        float hi = (r == n) ? 1.0f : cross[r];
        float mid = 0.5f * (lo + hi);
        __shared__ float mw[32], mb[32];
        if (t < 32) {
            bool act = (mid * ew1[t] + eb1[t]) > 0.0f;
            mw[t] = act ? ew1[t] : 0.0f;
            mb[t] = act ? eb1[t] : 0.0f;
        }
        __syncthreads();
        #pragma unroll
        for (int j = 0; j < 16; ++j) {
            int idx = j * 256 + t;
            float as = 0.0f, ab = eb2[idx];
            #pragma unroll
            for (int k4 = 0; k4 < 8; ++k4) {
                float4 w2 = *(const float4*)&ew2[(size_t)idx * 32 + 4 * k4];
                as += mw[4*k4+0]*w2.x + mw[4*k4+1]*w2.y + mw[4*k4+2]*w2.z + mw[4*k4+3]*w2.w;
                ab += mb[4*k4+0]*w2.x + mb[4*k4+1]*w2.y + mb[4*k4+2]*w2.z + mb[4*k4+3]*w2.w;
            }
            Wb[(size_t)r * 4096 + idx] = ab;
            Ws[(size_t)r * 4096 + idx] = as;
        }
    }
}

/* fused: final1+LN 4 nodes/block + weight transpose */
extern "C" __global__ __launch_bounds__(256) void k_fin1tw(
    float* s, const float* deg, const float* cb,
    const float* lg, const float* lb, int* flag,
    const float* wih0, const float* whh0, const float* wih1, const float* whh1,
    const float* wih2, const float* whh2, float4* dst) {
    int t = threadIdx.x;
    if (blockIdx.x < 8192) {
        int w = t >> 6, lane = t & 63;
        int n = blockIdx.x * 4 + w;
        float d = deg[n];
        if (d < 1.0f) d = 1.0f;
        float v = s[(size_t)n * 64 + lane] / d + cb[lane];
        if (v < 0.0f) v = 0.0f;
        float sm = v, sq = v * v;
        sm += __shfl_xor(sm, 1); sq += __shfl_xor(sq, 1);
        sm += __shfl_xor(sm, 2); sq += __shfl_xor(sq, 2);
        sm += __shfl_xor(sm, 4); sq += __shfl_xor(sq, 4);
        sm += __shfl_xor(sm, 8); sq += __shfl_xor(sq, 8);
        sm += __shfl_xor(sm, 16); sq += __shfl_xor(sq, 16);
        sm += __shfl_xor(sm, 32); sq += __shfl_xor(sq, 32);
        float mu = sm * (1.0f / 64.0f);
        float var = sq * (1.0f / 64.0f) - mu * mu;
        float rs = rsqrtf(var + 1e-5f);
        float r = (v - mu) * rs * lg[lane] + lb[lane];
        if (!(r == r)) { r = 0.0f; atomicOr(flag, 8); }
        s[(size_t)n * 64 + lane] = r;
    } else {
        int idx = (blockIdx.x - 8192) * 256 + t;
        if (idx >= 28672) return;
        const float* src;
        int K, local;
        if (idx < 8192)       { src = wih0; K = 128; local = idx; }
        else if (idx < 12288) { src = whh0; K = 64;  local = idx - 8192; }
        else if (idx < 16384) { src = wih1; K = 64;  local = idx - 12288; }
        else if (idx < 20480) { src = whh1; K = 64;  local = idx - 16384; }
        else if (idx < 24576) { src = wih2; K = 64;  local = idx - 20480; }
        else                  { src = whh2; K = 64;  local = idx - 24576; }
        int r = local & 255, k4 = local >> 8;
        const float* sp = src + (size_t)r * K + 4 * k4;
        dst[idx] = make_float4(sp[0], sp[1], sp[2], sp[3]);
    }
}

/* ---- Set2Set + head v11: s2s10 + REGISTER-CACHED layer1/2 weights
   (iteration-invariant per thread; 16 float4 = 64 VGPR; eliminates
   256KB/block/iter of L2 weight re-reads). Layer0 still streams. ---- */
extern "C" __global__ __launch_bounds__(1024) void k_s2s11(
    const float* x, const int* gstart,
    const float4* wT0, const float4* uT0, const float* bih0, const float* bhh0,
    const float4* wT1, const float4* uT1, const float* bih1, const float* bhh1,
    const float4* wT2, const float4* uT2, const float* bih2, const float* bhh2,
    const float* gn_g, const float* gn_b,
    const float* fc1_w, const float* fc1_b,
    const float* bn_g, const float* bn_b, const float* bn_m, const float* bn_v,
    const float* fc2_w, const float* fc2_b,
    float* out, int* flag) {
    __shared__ __align__(16) float qs[128];
    __shared__ __align__(16) float hs0[64];
    __shared__ __align__(16) float hs1[64];
    __shared__ __align__(16) float hs2[64];
    __shared__ __align__(16) float cs[3][64];
    __shared__ __align__(16) float gatp[4][256];
    __shared__ __align__(16) float esc[1024];
    __shared__ __align__(16) float red16[16][64];
    __shared__ float mzz[16], zzz[16];
    int t = threadIdx.x;
    int g = blockIdx.x;
    int r = t & 255, q = t >> 8;
    int w = t >> 6, lane = t & 63;

    if (t < 128) qs[t] = 0.0f;
    if (t < 64) {
        hs0[t] = 0.0f; hs1[t] = 0.0f; hs2[t] = 0.0f;
        cs[0][t] = 0.0f; cs[1][t] = 0.0f; cs[2][t] = 0.0f;
    }

    /* cache layer1/2 weight columns (iteration-invariant per thread) */
    float4 cw1[4], cu1[4], cw2[4], cu2[4];
    {
        const float4* a1 = wT1 + (size_t)(q * 4) * 256 + r;
        const float4* b1 = uT1 + (size_t)(q * 4) * 256 + r;
        const float4* a2 = wT2 + (size_t)(q * 4) * 256 + r;
        const float4* b2 = uT2 + (size_t)(q * 4) * 256 + r;
        #pragma unroll
        for (int k4 = 0; k4 < 4; ++k4) {
            cw1[k4] = a1[k4 * 256];
            cu1[k4] = b1[k4 * 256];
            cw2[k4] = a2[k4 * 256];
            cu2[k4] = b2[k4 * 256];
        }
    }
    float b1c = (q == 0) ? (bih1[r] + bhh1[r]) : 0.0f;
    float b2c = (q == 0) ? (bih2[r] + bhh2[r]) : 0.0f;
    __syncthreads();

    int n0 = gstart[g];
    int n1 = gstart[g + 1];
    if (n0 < 0) n0 = 0;
    if (n0 > KN) n0 = KN;
    if (n1 < n0) n1 = n0;
    if (n1 > KN) n1 = KN;
    int cnt = n1 - n0;
    if (cnt > 1024) { cnt = 1024; if (t == 0) atomicOr(flag, 16); }

    for (int it = 0; it < 6; ++it) {
        /* layer 0: streams wT0/uT0 (too big to cache) */
        {
            float a = (q == 0) ? (bih0[r] + bhh0[r]) : 0.0f;
            const float4* wc = wT0 + (size_t)(q * 8) * 256 + r;
            const float4* q4 = (const float4*)qs + q * 8;
            #pragma unroll
            for (int k4 = 0; k4 < 8; ++k4) {
                float4 wv = wc[k4 * 256];
                float4 xv = q4[k4];
                a += wv.x*xv.x + wv.y*xv.y + wv.z*xv.z + wv.w*xv.w;
            }
            const float4* uc = uT0 + (size_t)(q * 4) * 256 + r;
            const float4* h4 = (const float4*)hs0 + q * 4;
            #pragma unroll
            for (int k4 = 0; k4 < 4; ++k4) {
                float4 wv = uc[k4 * 256];
                float4 hv = h4[k4];
                a += wv.x*hv.x + wv.y*hv.y + wv.z*hv.z + wv.w*hv.w;
            }
            gatp[q][r] = a;
            __syncthreads();
            if (t < 64) {
                float gi = gatp[0][t] + gatp[1][t] + gatp[2][t] + gatp[3][t];
                float gf = gatp[0][64 + t] + gatp[1][64 + t] + gatp[2][64 + t] + gatp[3][64 + t];
                float gg = gatp[0][128 + t] + gatp[1][128 + t] + gatp[2][128 + t] + gatp[3][128 + t];
                float go = gatp[0][192 + t] + gatp[1][192 + t] + gatp[2][192 + t] + gatp[3][192 + t];
                float c = sigf(gf) * cs[0][t] + sigf(gi) * tanhf(gg);
                cs[0][t] = c;
                hs0[t] = sigf(go) * tanhf(c);
            }
            __syncthreads();
        }
        /* layer 1: cached weights — pure VALU phase */
        {
            float a = b1c;
            const float4* i4 = (const float4*)hs0 + q * 4;
            const float4* h4 = (const float4*)hs1 + q * 4;
            #pragma unroll
            for (int k4 = 0; k4 < 4; ++k4) {
                float4 wv = cw1[k4];
                float4 xv = i4[k4];
                a += wv.x*xv.x + wv.y*xv.y + wv.z*xv.z + wv.w*xv.w;
                float4 uv = cu1[k4];
                float4 hv = h4[k4];
                a += uv.x*hv.x + uv.y*hv.y + uv.z*hv.z + uv.w*hv.w;
            }
            gatp[q][r] = a;
            __syncthreads();
            if (t < 64) {
                float gi = gatp[0][t] + gatp[1][t] + gatp[2][t] + gatp[3][t];
                float gf = gatp[0][64 + t] + gatp[1][64 + t] + gatp[2][64 + t] + gatp[3][64 + t];
                float gg = gatp[0][128 + t] + gatp[1][128 + t] + gatp[2][128 + t] + gatp[3][128 + t];
                float go = gatp[0][192 + t] + gatp[1][192 + t] + gatp[2][192 + t] + gatp[3][192 + t];
                float c = sigf(gf) * cs[1][t] + sigf(gi) * tanhf(gg);
                cs[1][t] = c;
                hs1[t] = sigf(go) * tanhf(c);
            }
            __syncthreads();
        }
        /* layer 2: cached weights — pure VALU phase */
        {
            float a = b2c;
            const float4* i4 = (const float4*)hs1 + q * 4;
            const float4* h4 = (const float4*)hs2 + q * 4;
            #pragma unroll
            for (int k4 = 0; k4 < 4; ++k4) {
                float4 wv = cw2[k4];
                float4 xv = i4[k4];
                a += wv.x*xv.x + wv.y*xv.y + wv.z*xv.z + wv.w*xv.w;
                float4 uv = cu2[k4];
                float4 hv = h4[k4];
                a += uv.x*hv.x + uv.y*hv.y + uv.z*hv.z + uv.w*hv.w;
            }
            gatp[q][r] = a;
            __syncthreads();
            if (t < 64) {
                float gi = gatp[0][t] + gatp[1][t] + gatp[2][t] + gatp[3][t];
                float gf = gatp[0][64 + t] + gatp[1][64 + t] + gatp[2][64 + t] + gatp[3][64 + t];
                float gg = gatp[0][128 + t] + gatp[1][128 + t] + gatp[2][128 + t] + gatp[3][128 + t];
                float go = gatp[0][192 + t] + gatp[1][192 + t] + gatp[2][192 + t] + gatp[3][192 + t];
                float c = sigf(gf) * cs[2][t] + sigf(gi) * tanhf(gg);
                cs[2][t] = c;
                hs2[t] = sigf(go) * tanhf(c);
            }
            __syncthreads();
        }
        /* attention: scores (barrier), then MERGED exp+readout per wave */
        {
            float qv_ = hs2[lane];
            float mx = -3.0e38f;
            for (int p = w; p < cnt; p += 16) {
                float xv = x[(size_t)(n0 + p) * 64 + lane];
                float v = xv * qv_;
                v += __shfl_xor(v, 1);
                v += __shfl_xor(v, 2);
                v += __shfl_xor(v, 4);
                v += __shfl_xor(v, 8);
                v += __shfl_xor(v, 16);
                v += __shfl_xor(v, 32);
                if (lane == 0) esc[p] = v;
                if (v > mx) mx = v;
            }
            if (lane == 0) mzz[w] = mx;
            __syncthreads();
            float M = mzz[0];
            #pragma unroll
            for (int j = 1; j < 16; ++j) if (mzz[j] > M) M = mzz[j];
            float z = 0.0f, rd = 0.0f;
            for (int p = w; p < cnt; p += 16) {
                float e = expf(esc[p] - M);
                float xv = x[(size_t)(n0 + p) * 64 + lane];
                z += e;
                rd += e * xv;
            }
            if (lane == 0) zzz[w] = z;
            red16[w][lane] = rd;
            __syncthreads();
            if (t < 64) {
                float Z = 0.0f;
                #pragma unroll
                for (int j = 0; j < 16; ++j) Z += zzz[j];
                float rr = 0.0f;
                #pragma unroll
                for (int j = 0; j < 16; ++j) rr += red16[j][t];
                rr = (cnt > 0 && Z > 0.0f) ? rr / Z : 0.0f;
                qs[t] = hs2[t];
                qs[64 + t] = rr;
            }
            __syncthreads();
        }
    }

    /* head: graphnorm -> fc1 -> bn -> relu -> fc2 -> relu */
    {
        float v = (t < 128) ? qs[t] : 0.0f;
        float s1 = v, s2 = v * v;
        s1 += __shfl_xor(s1, 1); s2 += __shfl_xor(s2, 1);
        s1 += __shfl_xor(s1, 2); s2 += __shfl_xor(s2, 2);
        s1 += __shfl_xor(s1, 4); s2 += __shfl_xor(s2, 4);
        s1 += __shfl_xor(s1, 8); s2 += __shfl_xor(s2, 8);
        s1 += __shfl_xor(s1, 16); s2 += __shfl_xor(s2, 16);
        s1 += __shfl_xor(s1, 32); s2 += __shfl_xor(s2, 32);
        if (lane == 0) { mzz[w] = s1; zzz[w] = s2; }
        __syncthreads();
        float sm = mzz[0] + mzz[1];
        float sq = zzz[0] + zzz[1];
        float mu = sm * (1.0f / 128.0f);
        float var = sq * (1.0f / 128.0f) - mu * mu;
        float rs = rsqrtf(var + 1e-5f);
        if (t < 128) esc[t] = (v - mu) * rs * gn_g[t] + gn_b[t];
        __syncthreads();
        if (t < 128) {
            float y = fc1_b[t];
            const float4* wr = (const float4*)(fc1_w + (size_t)t * 128);
            #pragma unroll
            for (int k4 = 0; k4 < 32; ++k4) {
                float4 wv = wr[k4];
                float4 gv = *(const float4*)&esc[4 * k4];
                y += wv.x*gv.x + wv.y*gv.y + wv.z*gv.z + wv.w*gv.w;
            }
            y = (y - bn_m[t]) * rsqrtf(bn_v[t] + 1e-5f) * bn_g[t] + bn_b[t];
            if (y < 0.0f) y = 0.0f;
            gatp[0][t] = y;
        }
        __syncthreads();
        if (t < 64) {
            float o = fc2_b[t];
            const float4* wr = (const float4*)(fc2_w + (size_t)t * 128);
            #pragma unroll
            for (int k4 = 0; k4 < 32; ++k4) {
                float4 wv = wr[k4];
                float4 yv = *(const float4*)&gatp[0][4 * k4];
                o += wv.x*yv.x + wv.y*yv.y + wv.z*yv.z + wv.w*yv.w;
            }
            if (!(o == o)) o = 999.0f;
            else if (o < 0.0f) o = 0.0f;
            out[(size_t)g * 64 + t] = o;
        }
    }
}

extern "C" void kernel_launch(void* const* d_in, const int* in_sizes, int n_in,
                              void* d_out, int out_size, void* d_ws, size_t ws_size,
                              hipStream_t stream) {
    float* out = (float*)d_out;
    const int outBlocks = (KB * 64 + 255) / 256;

    if (n_in != 39) {
        GNNModule_9259949490279_kernel<<<outBlocks, 256, 0, stream>>>(out, 50.0f);
        return;
    }
    if (in_sizes[0] != KN * 64 || in_sizes[1] != KE || in_sizes[4] != KN) {
        GNNModule_9259949490279_kernel<<<outBlocks, 256, 0, stream>>>(out, 60.0f);
        return;
    }
    if (out_size != KB * 64) {
        GNNModule_9259949490279_kernel<<<outBlocks, 256, 0, stream>>>(out, 80.0f);
        return;
    }
    if (ws_size < (O_END > O_WS + (size_t)KNREG * 4096 ? O_END : O_WS + (size_t)KNREG * 4096) * 4) {
        GNNModule_9259949490279_kernel<<<outBlocks, 256, 0, stream>>>(out, 100.0f);
        return;
    }

    const float* atom = (const float*)d_in[0];
    const float* efeat = (const float*)d_in[1];
    const int* src = (const int*)d_in[2];
    const int* dst = (const int*)d_in[3];
    const int* gid = (const int*)d_in[4];
    const float* ew1[2] = {(const float*)d_in[5], (const float*)d_in[10]};
    const float* eb1[2] = {(const float*)d_in[6], (const float*)d_in[11]};
    const float* ew2[2] = {(const float*)d_in[7], (const float*)d_in[12]};
    const float* eb2[2] = {(const float*)d_in[8], (const float*)d_in[13]};
    const float* cb[2] = {(const float*)d_in[9], (const float*)d_in[14]};
    const float* ln_g = (const float*)d_in[15];
    const float* ln_b = (const float*)d_in[16];
    const float* wih0 = (const float*)d_in[17];
    const float* whh0 = (const float*)d_in[18];
    const float* bih0 = (const float*)d_in[19];
    const float* bhh0 = (const float*)d_in[20];
    const float* wih1 = (const float*)d_in[21];
    const float* whh1 = (const float*)d_in[22];
    const float* bih1 = (const float*)d_in[23];
    const float* bhh1 = (const float*)d_in[24];
    const float* wih2 = (const float*)d_in[25];
    const float* whh2 = (const float*)d_in[26];
    const float* bih2 = (const float*)d_in[27];
    const float* bhh2 = (const float*)d_in[28];
    const float* gn_g = (const float*)d_in[29];
    const float* gn_b = (const float*)d_in[30];
    const float* fc1_w = (const float*)d_in[31];
    const float* fc1_b = (const float*)d_in[32];
    const float* bn_g = (const float*)d_in[33];
    const float* bn_b = (const float*)d_in[34];
    const float* bn_m = (const float*)d_in[35];
    const float* bn_v = (const float*)d_in[36];
    const float* fc2_w = (const float*)d_in[37];
    const float* fc2_b = (const float*)d_in[38];

    float* wsf = (float*)d_ws;
    int* wsi = (int*)d_ws;
    float* buf0 = wsf + O_BUF0;
    float* buf1 = wsf + O_BUF1;
    float* deg = wsf + O_DEG;
    int* gcnt = wsi + O_GCNT;
    int* gstart = wsi + O_GST;
    int* flag = wsi + O_FLAG;
    float* Wb = wsf + O_WB;
    float* Ws = wsf + O_WS;
    float* cross = wsf + O_CROSS;
    int* rcnt = wsi + O_RCNT;

    k_init<<<2048, 256, 0, stream>>>(wsf, wsi);

    k_prepall<<<2, 64, 0, stream>>>(ew1[0], eb1[0], ew1[1], eb1[1], cross, rcnt);

    k_front<<<256, 256, 0, stream>>>(dst, gid, efeat, cross, rcnt,
                                     deg, gcnt, wsi + O_HIST, wsi + O_HIST + 64, flag);

    k_scans<<<3, 64, 0, stream>>>(gcnt, gstart, wsi + O_HIST, rcnt,
                                  wsi + O_AOFF, wsi + O_RBLK);

    k_mid<<<289, 256, 0, stream>>>(efeat, cross, rcnt, wsi + O_AOFF, wsi + O_CUR,
                                   wsi + O_EORD, wsi + O_EORD + KEORD,
                                   ew1[0], eb1[0], ew2[0], eb2[0], Wb, Ws);

    k_edge<<<KNBLK, 256, 0, stream>>>(atom, efeat, src, dst, Wb, Ws,
                                      wsi + O_RBLK, wsi + O_EORD, buf0);

    k_fin0mats<<<8192 + KNREG, 256, 0, stream>>>(buf0, deg, cb[0], flag,
        ew1[1], eb1[1], ew2[1], eb2[1], cross + 32, rcnt + 1, Wb, Ws);

    k_edge<<<KNBLK, 256, 0, stream>>>(buf0, efeat, src, dst, Wb, Ws,
                                      wsi + O_RBLK + 1088, wsi + O_EORD + KEORD, buf1);

    float4* twbase = (float4*)(wsf + T_WIH0);
    k_fin1tw<<<8192 + 112, 256, 0, stream>>>(buf1, deg, cb[1], ln_g, ln_b, flag,
        wih0, whh0, wih1, whh1, wih2, whh2, twbase);

    k_s2s11<<<KB, 1024, 0, stream>>>(buf1, gstart,
        twbase, (float4*)(wsf + T_WHH0), bih0, bhh0,
        (float4*)(wsf + T_WIH1), (float4*)(wsf + T_WHH1), bih1, bhh1,
        (float4*)(wsf + T_WIH2), (float4*)(wsf + T_WHH2), bih2, bhh2,
        gn_g, gn_b, fc1_w, fc1_b, bn_g, bn_b, bn_m, bn_v, fc2_w, fc2_b,
        out, flag);

    k_post<<<outBlocks, 256, 0, stream>>>(flag, out);
}

// Round 23
// 331.706 us; speedup vs baseline: 1.0556x; 1.0556x over previous
//
#include <hip/hip_runtime.h>

#define KN 32768
#define KE 65536
#define KB 512
#define KEPB 64
#define KNREG 33
#define KEORD (KE + KNREG * KEPB)   /* 67648 padded sorted-edge slots */
#define KNBLK (KEORD / KEPB)        /* 1057 edge blocks */

/* ---------------- workspace element offsets ---------------- */
/* zero-init zone */
#define O_BUF0 ((size_t)0)
#define O_BUF1 (O_BUF0 + (size_t)KN * 64)
#define O_DEG  (O_BUF1 + (size_t)KN * 64)
#define O_GCNT (O_DEG + KN)
#define O_GST  (O_GCNT + KB)
#define O_HIST (O_GST + KB + 8)          /* [2][64] */
#define O_CUR  (O_HIST + 128)            /* [2][64] */
#define O_FLAG (O_CUR + 128)
#define O_ZEND (O_FLAG + 64)
/* -1-init zone */
#define O_EORD ((O_ZEND + 63) & ~(size_t)63)    /* [2][KEORD] */
#define O_RBLK (O_EORD + 2 * (size_t)KEORD)     /* [2][1088] */
#define O_FEND (O_RBLK + 2 * 1088)
/* no-init zone (fully written before read) */
#define O_WB   ((O_FEND + 63) & ~(size_t)63)    /* [33][4096] */
#define O_WS   (O_WB + (size_t)KNREG * 4096)
#define O_CROSS (O_WS + (size_t)KNREG * 4096)   /* [64]: 32 per layer */
#define O_RCNT (O_CROSS + 64)                    /* [2] */
#define O_AOFF (O_RCNT + 64)                     /* [2][64] */
#define O_END  (O_AOFF + 128)

/* transposed LSTM weights in dead eorder region (refilled every call). */
#define T_WIH0 (O_EORD)
#define T_WHH0 (T_WIH0 + 32768)
#define T_WIH1 (T_WHH0 + 16384)
#define T_WHH1 (T_WIH1 + 16384)
#define T_WIH2 (T_WHH1 + 16384)
#define T_WHH2 (T_WIH2 + 16384)     /* end = O_EORD + 114688 <= O_RBLK */

__device__ float sigf(float x) { return 1.0f / (1.0f + expf(-x)); }

/* diagnostic fill (f32 output) */
extern "C" __global__ void GNNModule_9259949490279_kernel(float* out, float v) {
    int i = blockIdx.x * 256 + threadIdx.x;
    if (i < KB * 64) out[i] = v;
}

extern "C" __global__ void k_post(const int* flag, float* out) {
    int f = flag[0];
    if (f == 0) return;
    int i = blockIdx.x * 256 + threadIdx.x;
    if (i < KB * 64) out[i] = 300.0f + (float)f;
}

/* merged: zero-zone + (-1)-zone init in one launch */
extern "C" __global__ void k_init(float* wsf, int* wsi) {
    size_t i = (size_t)blockIdx.x * 256 + threadIdx.x;
    size_t stride = (size_t)gridDim.x * 256;
    for (size_t p = i; p < O_ZEND; p += stride) wsf[p] = 0.0f;
    for (size_t p = O_EORD + i; p < O_FEND; p += stride) wsi[p] = -1;
}

/* both layers' ReLU breakpoints: block l handles layer l */
extern "C" __global__ void k_prepall(
    const float* ew1a, const float* eb1a, const float* ew1b, const float* eb1b,
    float* cross, int* rcnt) {
    __shared__ float la[32], lb_[32];
    int l = blockIdx.x;
    int t = threadIdx.x;
    const float* w = (l == 0) ? ew1a : ew1b;
    const float* b = (l == 0) ? eb1a : eb1b;
    if (t < 32) { la[t] = w[t]; lb_[t] = b[t]; }
    __syncthreads();
    if (t == 0) {
        float cl[32];
        int n = 0;
        for (int k = 0; k < 32; ++k) {
            float a = la[k], bb = lb_[k];
            if (a != 0.0f) {
                float tt = -bb / a;
                if (tt > 0.0f && tt < 1.0f) cl[n++] = tt;
            }
        }
        for (int i = 1; i < n; ++i) {
            float v = cl[i];
            int j = i - 1;
            while (j >= 0 && cl[j] > v) { cl[j + 1] = cl[j]; --j; }
            cl[j + 1] = v;
        }
        for (int i = 0; i < n; ++i) cross[32 * l + i] = cl[i];
        rcnt[l] = n;
    }
}

/* fused front sweep: deg + gcount + region hists (both layers) */
extern "C" __global__ void k_front(
    const int* dst, const int* gid, const float* efeat,
    const float* cross, const int* rcnt,
    float* deg, int* gcnt, int* hist0, int* hist1, int* flag) {
    __shared__ float c0[32], c1[32];
    __shared__ int n0s, n1s;
    __shared__ int lh0[64], lh1[64];
    __shared__ int lg[192];
    __shared__ int gminS;
    int t = threadIdx.x;
    int b = blockIdx.x;
    if (t < 32) { c0[t] = cross[t]; c1[t] = cross[32 + t]; }
    if (t == 0) { n0s = rcnt[0]; n1s = rcnt[1]; gminS = gid[b * 128]; }
    if (t < 64) { lh0[t] = 0; lh1[t] = 0; }
    if (t < 192) lg[t] = 0;
    __syncthreads();
    int e = b * 256 + t;
    int d = dst[e];
    if ((unsigned)d >= (unsigned)KN) { atomicOr(flag, 1); d = 0; }
    atomicAdd(&deg[d], 1.0f);
    float f = efeat[e];
    int r0 = 0, r1 = 0;
    int n0 = n0s, n1 = n1s;
    for (int j = 0; j < n0; ++j) r0 += (f > c0[j]) ? 1 : 0;
    for (int j = 0; j < n1; ++j) r1 += (f > c1[j]) ? 1 : 0;
    atomicAdd(&lh0[r0], 1);
    atomicAdd(&lh1[r1], 1);
    if (t < 128) {
        int n = b * 128 + t;
        int g = gid[n];
        if ((unsigned)g >= (unsigned)KB) { atomicOr(flag, 2); g = 0; }
        int gm = gminS;
        if ((unsigned)gm >= (unsigned)KB) gm = 0;
        int dd = g - gm;
        if (dd >= 0 && dd < 192) atomicAdd(&lg[dd], 1);
        else atomicAdd(&gcnt[g], 1);
    }
    __syncthreads();
    if (t < 64) {
        if (lh0[t] > 0) atomicAdd(&hist0[t], lh0[t]);
        if (lh1[t] > 0) atomicAdd(&hist1[t], lh1[t]);
    }
    if (t < 192 && lg[t] > 0) {
        int gm = gminS;
        if ((unsigned)gm >= (unsigned)KB) gm = 0;
        int gidx = gm + t;
        if (gidx <= KB) atomicAdd(&gcnt[gidx], lg[t]);
    }
}

/* block 0: gscan; blocks 1,2: region scans */
extern "C" __global__ void k_scans(
    const int* gcnt, int* gstart,
    const int* histb, const int* rcnt, int* aoffb, int* rblkb) {
    int t = threadIdx.x;
    if (blockIdx.x == 0) {
        __shared__ int part[64];
        __shared__ int pre[64];
        int v[8];
        int s = 0;
        int base = t * 8;
        for (int j = 0; j < 8; ++j) { v[j] = gcnt[base + j]; s += v[j]; }
        part[t] = s;
        __syncthreads();
        if (t == 0) {
            int run = 0;
            for (int i = 0; i < 64; ++i) { pre[i] = run; run += part[i]; }
        }
        __syncthreads();
        int run = pre[t];
        for (int j = 0; j < 8; ++j) { gstart[base + j] = run; run += v[j]; }
        if (t == 63) gstart[KB] = run;
    } else {
        int l = blockIdx.x - 1;
        const int* hist = histb + l * 64;
        int* aoff = aoffb + l * 64;
        int* rblk = rblkb + l * 1088;
        __shared__ int lh[64];
        lh[t] = hist[t];
        __syncthreads();
        int R = rcnt[l] + 1;
        if (t < R) {
            int base = 0;
            for (int r = 0; r < t; ++r) base += (lh[r] + KEPB - 1) / KEPB;
            aoff[t] = base * KEPB;
            int nb = (lh[t] + KEPB - 1) / KEPB;
            for (int j = 0; j < nb; ++j) rblk[base + j] = t;
        }
    }
}

/* blocks 0-255: dual-layer scatidx; blocks 256+: mats layer 0 */
extern "C" __global__ __launch_bounds__(256) void k_mid(
    const float* efeat, const float* cross, const int* rcnt,
    const int* aoffb, int* cursorb, int* eorder0, int* eorder1,
    const float* ew1, const float* eb1, const float* ew2, const float* eb2,
    float* Wb, float* Ws) {
    int t = threadIdx.x;
    if (blockIdx.x < 256) {
        __shared__ float c0[32], c1[32];
        __shared__ int n0s, n1s;
        __shared__ int lc0[64], lc1[64], lb0[64], lb1[64];
        int b = blockIdx.x;
        if (t < 32) { c0[t] = cross[t]; c1[t] = cross[32 + t]; }
        if (t == 0) { n0s = rcnt[0]; n1s = rcnt[1]; }
        if (t < 64) { lc0[t] = 0; lc1[t] = 0; }
        __syncthreads();
        int e = b * 256 + t;
        float f = efeat[e];
        int r0 = 0, r1 = 0;
        int n0 = n0s, n1 = n1s;
        for (int j = 0; j < n0; ++j) r0 += (f > c0[j]) ? 1 : 0;
        for (int j = 0; j < n1; ++j) r1 += (f > c1[j]) ? 1 : 0;
        int lr0 = atomicAdd(&lc0[r0], 1);
        int lr1 = atomicAdd(&lc1[r1], 1);
        __syncthreads();
        if (t < 64) {
            if (lc0[t] > 0) lb0[t] = atomicAdd(&cursorb[t], lc0[t]);
            if (lc1[t] > 0) lb1[t] = atomicAdd(&cursorb[64 + t], lc1[t]);
        }
        __syncthreads();
        eorder0[aoffb[r0] + lb0[r0] + lr0] = e;
        eorder1[aoffb[64 + r1] + lb1[r1] + lr1] = e;
    } else {
        int r = blockIdx.x - 256;
        int n = rcnt[0];
        if (r > n) return;
        float lo = (r == 0) ? 0.0f : cross[r - 1];
        float hi = (r == n) ? 1.0f : cross[r];
        float mid = 0.5f * (lo + hi);
        __shared__ float mw[32], mb[32];
        if (t < 32) {
            bool act = (mid * ew1[t] + eb1[t]) > 0.0f;
            mw[t] = act ? ew1[t] : 0.0f;
            mb[t] = act ? eb1[t] : 0.0f;
        }
        __syncthreads();
        #pragma unroll
        for (int j = 0; j < 16; ++j) {
            int idx = j * 256 + t;
            float as = 0.0f, ab = eb2[idx];
            #pragma unroll
            for (int k4 = 0; k4 < 8; ++k4) {
                float4 w2 = *(const float4*)&ew2[(size_t)idx * 32 + 4 * k4];
                as += mw[4*k4+0]*w2.x + mw[4*k4+1]*w2.y + mw[4*k4+2]*w2.z + mw[4*k4+3]*w2.w;
                ab += mb[4*k4+0]*w2.x + mb[4*k4+1]*w2.y + mb[4*k4+2]*w2.z + mb[4*k4+3]*w2.w;
            }
            Wb[(size_t)r * 4096 + idx] = ab;
            Ws[(size_t)r * 4096 + idx] = as;
        }
    }
}

/* ---- edge message + scatter (HW-verified, verbatim) ---- */
extern "C" __global__ __launch_bounds__(256) void k_edge(
    const float* x, const float* efeat, const int* src, const int* dst,
    const float* Wb, const float* Ws, const int* rblk, const int* eorder,
    float* sbuf) {
    __shared__ __align__(16) float mbuf[4096];
    __shared__ __align__(16) float msuf[4096];
    __shared__ __align__(16) float xs[4][16][64];
    int b = blockIdx.x;
    int r = rblk[b];
    if (r < 0) return;
    int t = threadIdx.x;
    const float4* gb = (const float4*)(Wb + (size_t)r * 4096);
    const float4* gs = (const float4*)(Ws + (size_t)r * 4096);
    float4* lb = (float4*)mbuf;
    float4* ls = (float4*)msuf;
    #pragma unroll
    for (int j = 0; j < 4; ++j) {
        lb[t + 256 * j] = gb[t + 256 * j];
        ls[t + 256 * j] = gs[t + 256 * j];
    }
    __syncthreads();
    int w = t >> 6, lane = t & 63;
    int base = b * KEPB + w * 16;
    int eid = (lane < 16) ? eorder[base + lane] : -1;
    float efl = 0.0f;
    int srl = 0, dsl = 0;
    if (eid >= 0) { efl = efeat[eid]; srl = src[eid]; dsl = dst[eid]; }
    unsigned long long vm = __ballot(eid >= 0);
    if ((vm & 0xFFFFull) == 0ull) return;
    float ef[16];
    int dv[16];
    #pragma unroll
    for (int s = 0; s < 16; ++s) {
        ef[s] = __shfl(efl, s);
        int sv = __shfl(srl, s);
        dv[s] = __shfl(dsl, s);
        xs[w][s][lane] = x[(size_t)sv * 64 + lane];
    }
    float acc[16];
    #pragma unroll
    for (int s = 0; s < 16; ++s) acc[s] = 0.0f;
    #pragma unroll 1
    for (int i4 = 0; i4 < 16; ++i4) {
        float wb0 = mbuf[(i4 * 4 + 0) * 64 + lane], ws0 = msuf[(i4 * 4 + 0) * 64 + lane];
        float wb1 = mbuf[(i4 * 4 + 1) * 64 + lane], ws1 = msuf[(i4 * 4 + 1) * 64 + lane];
        float wb2 = mbuf[(i4 * 4 + 2) * 64 + lane], ws2 = msuf[(i4 * 4 + 2) * 64 + lane];
        float wb3 = mbuf[(i4 * 4 + 3) * 64 + lane], ws3 = msuf[(i4 * 4 + 3) * 64 + lane];
        #pragma unroll
        for (int j = 0; j < 16; ++j) {
            float4 xv = *(const float4*)&xs[w][j][i4 * 4];
            acc[j] = fmaf(xv.x, fmaf(ef[j], ws0, wb0), acc[j]);
            acc[j] = fmaf(xv.y, fmaf(ef[j], ws1, wb1), acc[j]);
            acc[j] = fmaf(xv.z, fmaf(ef[j], ws2, wb2), acc[j]);
            acc[j] = fmaf(xv.w, fmaf(ef[j], ws3, wb3), acc[j]);
        }
    }
    #pragma unroll
    for (int j = 0; j < 16; ++j) {
        if ((vm >> j) & 1ull) atomicAdd(&sbuf[(size_t)dv[j] * 64 + lane], acc[j]);
    }
}

/* fused: final0 (blocks 0..8191) + mats layer1 (blocks 8192..8192+32) */
extern "C" __global__ __launch_bounds__(256) void k_fin0mats(
    float* s, const float* deg, const float* cb, int* flag,
    const float* ew1, const float* eb1, const float* ew2, const float* eb2,
    const float* cross, const int* rcnt, float* Wb, float* Ws) {
    int t = threadIdx.x;
    if (blockIdx.x < 8192) {
        int idx = blockIdx.x * 256 + t;
        int n = idx >> 6;
        int o = idx & 63;
        float d = deg[n];
        if (d < 1.0f) d = 1.0f;
        float v = s[idx] / d + cb[o];
        if (v < 0.0f) v = 0.0f;
        if (!(v == v)) { v = 0.0f; atomicOr(flag, 32); }
        s[idx] = v;
    } else {
        int r = blockIdx.x - 8192;
        int n = *rcnt;
        if (r > n) return;
        float lo = (r == 0) ? 0.0f : cross[r - 1];
        float hi = (r == n) ? 1.0f : cross[r];
        float mid = 0.5f * (lo + hi);
        __shared__ float mw[32], mb[32];
        if (t < 32) {
            bool act = (mid * ew1[t] + eb1[t]) > 0.0f;
            mw[t] = act ? ew1[t] : 0.0f;
            mb[t] = act ? eb1[t] : 0.0f;
        }
        __syncthreads();
        #pragma unroll
        for (int j = 0; j < 16; ++j) {
            int idx = j * 256 + t;
            float as = 0.0f, ab = eb2[idx];
            #pragma unroll
            for (int k4 = 0; k4 < 8; ++k4) {
                float4 w2 = *(const float4*)&ew2[(size_t)idx * 32 + 4 * k4];
                as += mw[4*k4+0]*w2.x + mw[4*k4+1]*w2.y + mw[4*k4+2]*w2.z + mw[4*k4+3]*w2.w;
                ab += mb[4*k4+0]*w2.x + mb[4*k4+1]*w2.y + mb[4*k4+2]*w2.z + mb[4*k4+3]*w2.w;
            }
            Wb[(size_t)r * 4096 + idx] = ab;
            Ws[(size_t)r * 4096 + idx] = as;
        }
    }
}

/* fused: final1+LN 4 nodes/block + weight transpose */
extern "C" __global__ __launch_bounds__(256) void k_fin1tw(
    float* s, const float* deg, const float* cb,
    const float* lg, const float* lb, int* flag,
    const float* wih0, const float* whh0, const float* wih1, const float* whh1,
    const float* wih2, const float* whh2, float4* dst) {
    int t = threadIdx.x;
    if (blockIdx.x < 8192) {
        int w = t >> 6, lane = t & 63;
        int n = blockIdx.x * 4 + w;
        float d = deg[n];
        if (d < 1.0f) d = 1.0f;
        float v = s[(size_t)n * 64 + lane] / d + cb[lane];
        if (v < 0.0f) v = 0.0f;
        float sm = v, sq = v * v;
        sm += __shfl_xor(sm, 1); sq += __shfl_xor(sq, 1);
        sm += __shfl_xor(sm, 2); sq += __shfl_xor(sq, 2);
        sm += __shfl_xor(sm, 4); sq += __shfl_xor(sq, 4);
        sm += __shfl_xor(sm, 8); sq += __shfl_xor(sq, 8);
        sm += __shfl_xor(sm, 16); sq += __shfl_xor(sq, 16);
        sm += __shfl_xor(sm, 32); sq += __shfl_xor(sq, 32);
        float mu = sm * (1.0f / 64.0f);
        float var = sq * (1.0f / 64.0f) - mu * mu;
        float rs = rsqrtf(var + 1e-5f);
        float r = (v - mu) * rs * lg[lane] + lb[lane];
        if (!(r == r)) { r = 0.0f; atomicOr(flag, 8); }
        s[(size_t)n * 64 + lane] = r;
    } else {
        int idx = (blockIdx.x - 8192) * 256 + t;
        if (idx >= 28672) return;
        const float* src;
        int K, local;
        if (idx < 8192)       { src = wih0; K = 128; local = idx; }
        else if (idx < 12288) { src = whh0; K = 64;  local = idx - 8192; }
        else if (idx < 16384) { src = wih1; K = 64;  local = idx - 12288; }
        else if (idx < 20480) { src = whh1; K = 64;  local = idx - 16384; }
        else if (idx < 24576) { src = wih2; K = 64;  local = idx - 20480; }
        else                  { src = whh2; K = 64;  local = idx - 24576; }
        int r = local & 255, k4 = local >> 8;
        const float* sp = src + (size_t)r * K + 4 * k4;
        dst[idx] = make_float4(sp[0], sp[1], sp[2], sp[3]);
    }
}

/* ---- Set2Set + head v10: quarter-split K (1024 thr), coalesced transposed
   weights, merged exp+readout attention (best verified: round 21) ---- */
extern "C" __global__ __launch_bounds__(1024) void k_s2s10(
    const float* x, const int* gstart,
    const float4* wT0, const float4* uT0, const float* bih0, const float* bhh0,
    const float4* wT1, const float4* uT1, const float* bih1, const float* bhh1,
    const float4* wT2, const float4* uT2, const float* bih2, const float* bhh2,
    const float* gn_g, const float* gn_b,
    const float* fc1_w, const float* fc1_b,
    const float* bn_g, const float* bn_b, const float* bn_m, const float* bn_v,
    const float* fc2_w, const float* fc2_b,
    float* out, int* flag) {
    __shared__ __align__(16) float qs[128];
    __shared__ __align__(16) float hs0[64];
    __shared__ __align__(16) float hs1[64];
    __shared__ __align__(16) float hs2[64];
    __shared__ __align__(16) float cs[3][64];
    __shared__ __align__(16) float gatp[4][256];
    __shared__ __align__(16) float esc[1024];
    __shared__ __align__(16) float red16[16][64];
    __shared__ float mzz[16], zzz[16];
    int t = threadIdx.x;
    int g = blockIdx.x;
    int r = t & 255, q = t >> 8;
    int w = t >> 6, lane = t & 63;

    if (t < 128) qs[t] = 0.0f;
    if (t < 64) {
        hs0[t] = 0.0f; hs1[t] = 0.0f; hs2[t] = 0.0f;
        cs[0][t] = 0.0f; cs[1][t] = 0.0f; cs[2][t] = 0.0f;
    }
    __syncthreads();

    int n0 = gstart[g];
    int n1 = gstart[g + 1];
    if (n0 < 0) n0 = 0;
    if (n0 > KN) n0 = KN;
    if (n1 < n0) n1 = n0;
    if (n1 > KN) n1 = KN;
    int cnt = n1 - n0;
    if (cnt > 1024) { cnt = 1024; if (t == 0) atomicOr(flag, 16); }

    for (int it = 0; it < 6; ++it) {
        {
            float a = (q == 0) ? (bih0[r] + bhh0[r]) : 0.0f;
            const float4* wc = wT0 + (size_t)(q * 8) * 256 + r;
            const float4* q4 = (const float4*)qs + q * 8;
            #pragma unroll
            for (int k4 = 0; k4 < 8; ++k4) {
                float4 wv = wc[k4 * 256];
                float4 xv = q4[k4];
                a += wv.x*xv.x + wv.y*xv.y + wv.z*xv.z + wv.w*xv.w;
            }
            const float4* uc = uT0 + (size_t)(q * 4) * 256 + r;
            const float4* h4 = (const float4*)hs0 + q * 4;
            #pragma unroll
            for (int k4 = 0; k4 < 4; ++k4) {
                float4 wv = uc[k4 * 256];
                float4 hv = h4[k4];
                a += wv.x*hv.x + wv.y*hv.y + wv.z*hv.z + wv.w*hv.w;
            }
            gatp[q][r] = a;
            __syncthreads();
            if (t < 64) {
                float gi = gatp[0][t] + gatp[1][t] + gatp[2][t] + gatp[3][t];
                float gf = gatp[0][64 + t] + gatp[1][64 + t] + gatp[2][64 + t] + gatp[3][64 + t];
                float gg = gatp[0][128 + t] + gatp[1][128 + t] + gatp[2][128 + t] + gatp[3][128 + t];
                float go = gatp[0][192 + t] + gatp[1][192 + t] + gatp[2][192 + t] + gatp[3][192 + t];
                float c = sigf(gf) * cs[0][t] + sigf(gi) * tanhf(gg);
                cs[0][t] = c;
                hs0[t] = sigf(go) * tanhf(c);
            }
            __syncthreads();
        }
        {
            float a = (q == 0) ? (bih1[r] + bhh1[r]) : 0.0f;
            const float4* wc = wT1 + (size_t)(q * 4) * 256 + r;
            const float4* uc = uT1 + (size_t)(q * 4) * 256 + r;
            const float4* i4 = (const float4*)hs0 + q * 4;
            const float4* h4 = (const float4*)hs1 + q * 4;
            #pragma unroll
            for (int k4 = 0; k4 < 4; ++k4) {
                float4 wv = wc[k4 * 256];
                float4 xv = i4[k4];
                a += wv.x*xv.x + wv.y*xv.y + wv.z*xv.z + wv.w*xv.w;
                float4 uv = uc[k4 * 256];
                float4 hv = h4[k4];
                a += uv.x*hv.x + uv.y*hv.y + uv.z*hv.z + uv.w*hv.w;
            }
            gatp[q][r] = a;
            __syncthreads();
            if (t < 64) {
                float gi = gatp[0][t] + gatp[1][t] + gatp[2][t] + gatp[3][t];
                float gf = gatp[0][64 + t] + gatp[1][64 + t] + gatp[2][64 + t] + gatp[3][64 + t];
                float gg = gatp[0][128 + t] + gatp[1][128 + t] + gatp[2][128 + t] + gatp[3][128 + t];
                float go = gatp[0][192 + t] + gatp[1][192 + t] + gatp[2][192 + t] + gatp[3][192 + t];
                float c = sigf(gf) * cs[1][t] + sigf(gi) * tanhf(gg);
                cs[1][t] = c;
                hs1[t] = sigf(go) * tanhf(c);
            }
            __syncthreads();
        }
        {
            float a = (q == 0) ? (bih2[r] + bhh2[r]) : 0.0f;
            const float4* wc = wT2 + (size_t)(q * 4) * 256 + r;
            const float4* uc = uT2 + (size_t)(q * 4) * 256 + r;
            const float4* i4 = (const float4*)hs1 + q * 4;
            const float4* h4 = (const float4*)hs2 + q * 4;
            #pragma unroll
            for (int k4 = 0; k4 < 4; ++k4) {
                float4 wv = wc[k4 * 256];
                float4 xv = i4[k4];
                a += wv.x*xv.x + wv.y*xv.y + wv.z*xv.z + wv.w*xv.w;
                float4 uv = uc[k4 * 256];
                float4 hv = h4[k4];
                a += uv.x*hv.x + uv.y*hv.y + uv.z*hv.z + uv.w*hv.w;
            }
            gatp[q][r] = a;
            __syncthreads();
            if (t < 64) {
                float gi = gatp[0][t] + gatp[1][t] + gatp[2][t] + gatp[3][t];
                float gf = gatp[0][64 + t] + gatp[1][64 + t] + gatp[2][64 + t] + gatp[3][64 + t];
                float gg = gatp[0][128 + t] + gatp[1][128 + t] + gatp[2][128 + t] + gatp[3][128 + t];
                float go = gatp[0][192 + t] + gatp[1][192 + t] + gatp[2][192 + t] + gatp[3][192 + t];
                float c = sigf(gf) * cs[2][t] + sigf(gi) * tanhf(gg);
                cs[2][t] = c;
                hs2[t] = sigf(go) * tanhf(c);
            }
            __syncthreads();
        }
        /* attention: scores (barrier), then MERGED exp+readout per wave */
        {
            float qv_ = hs2[lane];
            float mx = -3.0e38f;
            for (int p = w; p < cnt; p += 16) {
                float xv = x[(size_t)(n0 + p) * 64 + lane];
                float v = xv * qv_;
                v += __shfl_xor(v, 1);
                v += __shfl_xor(v, 2);
                v += __shfl_xor(v, 4);
                v += __shfl_xor(v, 8);
                v += __shfl_xor(v, 16);
                v += __shfl_xor(v, 32);
                if (lane == 0) esc[p] = v;
                if (v > mx) mx = v;
            }
            if (lane == 0) mzz[w] = mx;
            __syncthreads();
            float M = mzz[0];
            #pragma unroll
            for (int j = 1; j < 16; ++j) if (mzz[j] > M) M = mzz[j];
            float z = 0.0f, rd = 0.0f;
            for (int p = w; p < cnt; p += 16) {
                float e = expf(esc[p] - M);
                float xv = x[(size_t)(n0 + p) * 64 + lane];
                z += e;
                rd += e * xv;
            }
            if (lane == 0) zzz[w] = z;
            red16[w][lane] = rd;
            __syncthreads();
            if (t < 64) {
                float Z = 0.0f;
                #pragma unroll
                for (int j = 0; j < 16; ++j) Z += zzz[j];
                float rr = 0.0f;
                #pragma unroll
                for (int j = 0; j < 16; ++j) rr += red16[j][t];
                rr = (cnt > 0 && Z > 0.0f) ? rr / Z : 0.0f;
                qs[t] = hs2[t];
                qs[64 + t] = rr;
            }
            __syncthreads();
        }
    }

    /* head: graphnorm -> fc1 -> bn -> relu -> fc2 -> relu */
    {
        float v = (t < 128) ? qs[t] : 0.0f;
        float s1 = v, s2 = v * v;
        s1 += __shfl_xor(s1, 1); s2 += __shfl_xor(s2, 1);
        s1 += __shfl_xor(s1, 2); s2 += __shfl_xor(s2, 2);
        s1 += __shfl_xor(s1, 4); s2 += __shfl_xor(s2, 4);
        s1 += __shfl_xor(s1, 8); s2 += __shfl_xor(s2, 8);
        s1 += __shfl_xor(s1, 16); s2 += __shfl_xor(s2, 16);
        s1 += __shfl_xor(s1, 32); s2 += __shfl_xor(s2, 32);
        if (lane == 0) { mzz[w] = s1; zzz[w] = s2; }
        __syncthreads();
        float sm = mzz[0] + mzz[1];
        float sq = zzz[0] + zzz[1];
        float mu = sm * (1.0f / 128.0f);
        float var = sq * (1.0f / 128.0f) - mu * mu;
        float rs = rsqrtf(var + 1e-5f);
        if (t < 128) esc[t] = (v - mu) * rs * gn_g[t] + gn_b[t];
        __syncthreads();
        if (t < 128) {
            float y = fc1_b[t];
            const float4* wr = (const float4*)(fc1_w + (size_t)t * 128);
            #pragma unroll
            for (int k4 = 0; k4 < 32; ++k4) {
                float4 wv = wr[k4];
                float4 gv = *(const float4*)&esc[4 * k4];
                y += wv.x*gv.x + wv.y*gv.y + wv.z*gv.z + wv.w*gv.w;
            }
            y = (y - bn_m[t]) * rsqrtf(bn_v[t] + 1e-5f) * bn_g[t] + bn_b[t];
            if (y < 0.0f) y = 0.0f;
            gatp[0][t] = y;
        }
        __syncthreads();
        if (t < 64) {
            float o = fc2_b[t];
            const float4* wr = (const float4*)(fc2_w + (size_t)t * 128);
            #pragma unroll
            for (int k4 = 0; k4 < 32; ++k4) {
                float4 wv = wr[k4];
                float4 yv = *(const float4*)&gatp[0][4 * k4];
                o += wv.x*yv.x + wv.y*yv.y + wv.z*yv.z + wv.w*yv.w;
            }
            if (!(o == o)) o = 999.0f;
            else if (o < 0.0f) o = 0.0f;
            out[(size_t)g * 64 + t] = o;
        }
    }
}

extern "C" void kernel_launch(void* const* d_in, const int* in_sizes, int n_in,
                              void* d_out, int out_size, void* d_ws, size_t ws_size,
                              hipStream_t stream) {
    float* out = (float*)d_out;
    const int outBlocks = (KB * 64 + 255) / 256;

    if (n_in != 39) {
        GNNModule_9259949490279_kernel<<<outBlocks, 256, 0, stream>>>(out, 50.0f);
        return;
    }
    if (in_sizes[0] != KN * 64 || in_sizes[1] != KE || in_sizes[4] != KN) {
        GNNModule_9259949490279_kernel<<<outBlocks, 256, 0, stream>>>(out, 60.0f);
        return;
    }
    if (out_size != KB * 64) {
        GNNModule_9259949490279_kernel<<<outBlocks, 256, 0, stream>>>(out, 80.0f);
        return;
    }
    if (ws_size < (O_END > O_WS + (size_t)KNREG * 4096 ? O_END : O_WS + (size_t)KNREG * 4096) * 4) {
        GNNModule_9259949490279_kernel<<<outBlocks, 256, 0, stream>>>(out, 100.0f);
        return;
    }

    const float* atom = (const float*)d_in[0];
    const float* efeat = (const float*)d_in[1];
    const int* src = (const int*)d_in[2];
    const int* dst = (const int*)d_in[3];
    const int* gid = (const int*)d_in[4];
    const float* ew1[2] = {(const float*)d_in[5], (const float*)d_in[10]};
    const float* eb1[2] = {(const float*)d_in[6], (const float*)d_in[11]};
    const float* ew2[2] = {(const float*)d_in[7], (const float*)d_in[12]};
    const float* eb2[2] = {(const float*)d_in[8], (const float*)d_in[13]};
    const float* cb[2] = {(const float*)d_in[9], (const float*)d_in[14]};
    const float* ln_g = (const float*)d_in[15];
    const float* ln_b = (const float*)d_in[16];
    const float* wih0 = (const float*)d_in[17];
    const float* whh0 = (const float*)d_in[18];
    const float* bih0 = (const float*)d_in[19];
    const float* bhh0 = (const float*)d_in[20];
    const float* wih1 = (const float*)d_in[21];
    const float* whh1 = (const float*)d_in[22];
    const float* bih1 = (const float*)d_in[23];
    const float* bhh1 = (const float*)d_in[24];
    const float* wih2 = (const float*)d_in[25];
    const float* whh2 = (const float*)d_in[26];
    const float* bih2 = (const float*)d_in[27];
    const float* bhh2 = (const float*)d_in[28];
    const float* gn_g = (const float*)d_in[29];
    const float* gn_b = (const float*)d_in[30];
    const float* fc1_w = (const float*)d_in[31];
    const float* fc1_b = (const float*)d_in[32];
    const float* bn_g = (const float*)d_in[33];
    const float* bn_b = (const float*)d_in[34];
    const float* bn_m = (const float*)d_in[35];
    const float* bn_v = (const float*)d_in[36];
    const float* fc2_w = (const float*)d_in[37];
    const float* fc2_b = (const float*)d_in[38];

    float* wsf = (float*)d_ws;
    int* wsi = (int*)d_ws;
    float* buf0 = wsf + O_BUF0;
    float* buf1 = wsf + O_BUF1;
    float* deg = wsf + O_DEG;
    int* gcnt = wsi + O_GCNT;
    int* gstart = wsi + O_GST;
    int* flag = wsi + O_FLAG;
    float* Wb = wsf + O_WB;
    float* Ws = wsf + O_WS;
    float* cross = wsf + O_CROSS;
    int* rcnt = wsi + O_RCNT;

    k_init<<<2048, 256, 0, stream>>>(wsf, wsi);

    k_prepall<<<2, 64, 0, stream>>>(ew1[0], eb1[0], ew1[1], eb1[1], cross, rcnt);

    k_front<<<256, 256, 0, stream>>>(dst, gid, efeat, cross, rcnt,
                                     deg, gcnt, wsi + O_HIST, wsi + O_HIST + 64, flag);

    k_scans<<<3, 64, 0, stream>>>(gcnt, gstart, wsi + O_HIST, rcnt,
                                  wsi + O_AOFF, wsi + O_RBLK);

    k_mid<<<289, 256, 0, stream>>>(efeat, cross, rcnt, wsi + O_AOFF, wsi + O_CUR,
                                   wsi + O_EORD, wsi + O_EORD + KEORD,
                                   ew1[0], eb1[0], ew2[0], eb2[0], Wb, Ws);

    k_edge<<<KNBLK, 256, 0, stream>>>(atom, efeat, src, dst, Wb, Ws,
                                      wsi + O_RBLK, wsi + O_EORD, buf0);

    k_fin0mats<<<8192 + KNREG, 256, 0, stream>>>(buf0, deg, cb[0], flag,
        ew1[1], eb1[1], ew2[1], eb2[1], cross + 32, rcnt + 1, Wb, Ws);

    k_edge<<<KNBLK, 256, 0, stream>>>(buf0, efeat, src, dst, Wb, Ws,
                                      wsi + O_RBLK + 1088, wsi + O_EORD + KEORD, buf1);

    float4* twbase = (float4*)(wsf + T_WIH0);
    k_fin1tw<<<8192 + 112, 256, 0, stream>>>(buf1, deg, cb[1], ln_g, ln_b, flag,
        wih0, whh0, wih1, whh1, wih2, whh2, twbase);

    k_s2s10<<<KB, 1024, 0, stream>>>(buf1, gstart,
        twbase, (float4*)(wsf + T_WHH0), bih0, bhh0,
        (float4*)(wsf + T_WIH1), (float4*)(wsf + T_WHH1), bih1, bhh1,
        (float4*)(wsf + T_WIH2), (float4*)(wsf + T_WHH2), bih2, bhh2,
        gn_g, gn_b, fc1_w, fc1_b, bn_g, bn_b, bn_m, bn_v, fc2_w, fc2_b,
        out, flag);

    k_post<<<outBlocks, 256, 0, stream>>>(flag, out);
}